// Round 1
// baseline (6214.363 us; speedup 1.0000x reference)
//
#include <hip/hip_runtime.h>
#include <math.h>

#define VOCABSZ 32000
#define EMBD 512
#define HIDD 512
#define BSZ 32
#define TLEN 32
#define G4 2048            // 4*HID
#define NBLK_LOG 250       // 32000 / 128
#define COLS_PER_BLK 128

__device__ __forceinline__ float sigmoidf_(float x) { return 1.f / (1.f + expf(-x)); }

// ---------------------------------------------------------------------------
// init: h <- x, c <- 0, inp <- emb[START], loss <- 0, detect coin dtype
// ---------------------------------------------------------------------------
__global__ void init_kernel(const float* __restrict__ x,
                            const float* __restrict__ emb,
                            const void* __restrict__ coin,
                            float* __restrict__ h, float* __restrict__ c,
                            float* __restrict__ inp,
                            float* __restrict__ loss, int* __restrict__ flag) {
    int tid = threadIdx.x;
    if (tid == 0) {
        // Detect whether coin is stored as int32 (words 0/1) or uint8 bools
        // (packed bytes -> words like 0x00010001 > 1). Only first 1KB read:
        // valid under both layouts.
        const unsigned int* cw = (const unsigned int*)coin;
        int f = 0;
        for (int i = 0; i < 256; ++i) if (cw[i] > 1u) f = 1;
        *flag = f;
        *loss = 0.f;
    }
    for (int i = tid; i < BSZ * HIDD; i += blockDim.x) {
        h[i] = x[i];
        c[i] = 0.f;
        inp[i] = emb[1 * EMBD + (i & (EMBD - 1))];  // START = 1
    }
}

// ---------------------------------------------------------------------------
// LSTM cell: gates = inp@Wi + h@Wh + b ; update c (in place), h (dst buffer)
// grid 32 blocks x 256 thr. Block covers 16 gate-cols j (all 4 gates, all 32
// rows). Thread: col = tid&15, rowgroup = tid>>4 -> 2 rows.
// ---------------------------------------------------------------------------
__global__ __launch_bounds__(256) void cell_kernel(
    const float* __restrict__ inp, const float* __restrict__ Wi,
    const float* __restrict__ Wh, const float* __restrict__ bias,
    const float* __restrict__ hsrc, float* __restrict__ c,
    float* __restrict__ hdst) {
    __shared__ float s_x[32][64];
    int tid = threadIdx.x;
    int cidx = tid & 15;
    int rowg = tid >> 4;                 // 0..15
    int j = blockIdx.x * 16 + cidx;      // 0..511
    float acc[2][4] = {{0.f,0.f,0.f,0.f},{0.f,0.f,0.f,0.f}};

    for (int kt = 0; kt < 16; ++kt) {
        int k0 = kt * 64;
        const float* src = (k0 < 512) ? (inp + k0) : (hsrc + (k0 - 512));
        for (int i = tid; i < 32 * 64; i += 256) {
            int r = i >> 6, kk = i & 63;
            s_x[r][kk] = src[r * HIDD + kk];
        }
        __syncthreads();
        const float* W = (k0 < 512) ? (Wi + (size_t)k0 * G4)
                                    : (Wh + (size_t)(k0 - 512) * G4);
        for (int kk = 0; kk < 64; ++kk) {
            const float* Wrow = W + (size_t)kk * G4;
            float w0 = Wrow[j];
            float w1 = Wrow[j + 512];
            float w2 = Wrow[j + 1024];
            float w3 = Wrow[j + 1536];
            float x0 = s_x[2 * rowg][kk];
            float x1 = s_x[2 * rowg + 1][kk];
            acc[0][0] += x0 * w0; acc[0][1] += x0 * w1;
            acc[0][2] += x0 * w2; acc[0][3] += x0 * w3;
            acc[1][0] += x1 * w0; acc[1][1] += x1 * w1;
            acc[1][2] += x1 * w2; acc[1][3] += x1 * w3;
        }
        __syncthreads();
    }
    #pragma unroll
    for (int rr = 0; rr < 2; ++rr) {
        int r = 2 * rowg + rr;
        float i_ = acc[rr][0] + bias[j];
        float f_ = acc[rr][1] + bias[j + 512];
        float g_ = acc[rr][2] + bias[j + 1024];
        float o_ = acc[rr][3] + bias[j + 1536];
        float ci = c[r * HIDD + j];
        float cn = sigmoidf_(f_) * ci + sigmoidf_(i_) * tanhf(g_);
        float hn = sigmoidf_(o_) * tanhf(cn);
        c[r * HIDD + j] = cn;
        hdst[r * HIDD + j] = hn;
    }
}

// ---------------------------------------------------------------------------
// logits: out[32, 32000] = h @ Wo + bo, fused per-block softmax partials.
// grid 250 blocks x 256 thr; block = 128 vocab cols. Thread: col = tid&127,
// rg = tid>>7 -> 16 rows each. Partials per (block,row):
//   [0]=max [1]=sum exp(x-max) [2]=argmax idx (bitcast) [3]=label logit
//   [4]=STOP logit   (-inf when col not in this block)
// ---------------------------------------------------------------------------
__global__ __launch_bounds__(256) void logits_kernel(
    const float* __restrict__ h, const float* __restrict__ Wo,
    const float* __restrict__ bo, const int* __restrict__ labels,
    float* __restrict__ part, int t) {
    __shared__ float s_h[32][64];
    __shared__ float s_out[32][COLS_PER_BLK];
    int tid = threadIdx.x;
    int cl = tid & 127;
    int rg = tid >> 7;  // 0 or 1
    int col = blockIdx.x * COLS_PER_BLK + cl;
    float acc[16];
    #pragma unroll
    for (int i = 0; i < 16; ++i) acc[i] = 0.f;

    for (int kt = 0; kt < 8; ++kt) {
        int k0 = kt * 64;
        for (int i = tid; i < 32 * 64; i += 256) {
            int r = i >> 6, kk = i & 63;
            s_h[r][kk] = h[r * HIDD + k0 + kk];
        }
        __syncthreads();
        for (int kk = 0; kk < 64; ++kk) {
            float w = Wo[(size_t)(k0 + kk) * VOCABSZ + col];
            #pragma unroll
            for (int rr = 0; rr < 16; ++rr)
                acc[rr] += s_h[rg * 16 + rr][kk] * w;
        }
        __syncthreads();
    }
    float bcol = bo[col];
    #pragma unroll
    for (int rr = 0; rr < 16; ++rr) s_out[rg * 16 + rr][cl] = acc[rr] + bcol;
    __syncthreads();

    // per-row partial reduction over the 128 cols: 8 threads per row
    int row = tid >> 3;
    int slot = tid & 7;
    float m = -INFINITY; int mi = 0;
    for (int cc = slot; cc < COLS_PER_BLK; cc += 8) {
        float v = s_out[row][cc];
        int gidx = blockIdx.x * COLS_PER_BLK + cc;
        if (v > m || (v == m && gidx < mi)) { m = v; mi = gidx; }
    }
    #pragma unroll
    for (int d = 1; d < 8; d <<= 1) {
        float om = __shfl_xor(m, d);
        int omi = __shfl_xor(mi, d);
        if (om > m || (om == m && omi < mi)) { m = om; mi = omi; }
    }
    float s = 0.f;
    for (int cc = slot; cc < COLS_PER_BLK; cc += 8) s += expf(s_out[row][cc] - m);
    #pragma unroll
    for (int d = 1; d < 8; d <<= 1) s += __shfl_xor(s, d);

    if (slot == 0) {
        float* p = part + (size_t)(blockIdx.x * 32 + row) * 8;
        p[0] = m;
        p[1] = s;
        p[2] = __int_as_float(mi);
        int lab = labels[row * TLEN + t];
        int lc = lab - blockIdx.x * COLS_PER_BLK;
        p[3] = (lc >= 0 && lc < COLS_PER_BLK) ? s_out[row][lc] : -INFINITY;
        int sc = 2 - blockIdx.x * COLS_PER_BLK;  // STOP = 2
        p[4] = (sc >= 0 && sc < COLS_PER_BLK) ? s_out[row][sc] : -INFINITY;
    }
}

// ---------------------------------------------------------------------------
// reduce: combine 250 block-partials per row -> logZ, ce, argmax; accumulate
// loss; pick next token (scheduled sampling); gather emb row into inp.
// 1 block x 256 thr: 8 slots per row.
// ---------------------------------------------------------------------------
__global__ __launch_bounds__(256) void reduce_kernel(
    const float* __restrict__ part, const int* __restrict__ labels,
    const void* __restrict__ coin, const int* __restrict__ flag,
    const float* __restrict__ emb, float* __restrict__ inp,
    float* __restrict__ loss, float* __restrict__ out,
    int t, int is_final) {
    __shared__ float s_ce[32];
    __shared__ int s_tok[32];
    int tid = threadIdx.x;
    int row = tid >> 3, slot = tid & 7;

    float M = -INFINITY, S = 0.f;
    float av = -INFINITY; int ai = 0;
    float lv = -INFINITY, sv = -INFINITY;
    for (int ib = slot; ib < NBLK_LOG; ib += 8) {
        const float* p = part + (size_t)(ib * 32 + row) * 8;
        float pm = p[0], ps = p[1];
        int pi = __float_as_int(p[2]);
        float nM = fmaxf(M, pm);
        S = S * expf(M - nM) + ps * expf(pm - nM);
        M = nM;
        if (pm > av || (pm == av && pi < ai)) { av = pm; ai = pi; }
        lv = fmaxf(lv, p[3]);
        sv = fmaxf(sv, p[4]);
    }
    #pragma unroll
    for (int d = 1; d < 8; d <<= 1) {
        float oM = __shfl_xor(M, d), oS = __shfl_xor(S, d);
        float nM = fmaxf(M, oM);
        S = S * expf(M - nM) + oS * expf(oM - nM);
        M = nM;
        float oav = __shfl_xor(av, d); int oai = __shfl_xor(ai, d);
        if (oav > av || (oav == av && oai < ai)) { av = oav; ai = oai; }
        lv = fmaxf(lv, __shfl_xor(lv, d));
        sv = fmaxf(sv, __shfl_xor(sv, d));
    }
    if (slot == 0) {
        float logZ = M + logf(S);
        float ce = logZ - (is_final ? sv : lv);
        s_ce[row] = ce;
        if (!is_final) {
            int lab = labels[row * TLEN + t];
            int cn;
            if (*flag) cn = ((const unsigned char*)coin)[row * TLEN + t];
            else       cn = ((const int*)coin)[row * TLEN + t];
            s_tok[row] = cn ? ai : lab;
        }
    }
    __syncthreads();
    if (tid == 0) {
        float tot = 0.f;
        for (int r = 0; r < 32; ++r) tot += s_ce[r];
        float nl = *loss + tot;
        *loss = nl;
        if (is_final) *out = nl / 32.f;
    }
    if (!is_final) {
        __syncthreads();
        for (int i = tid; i < BSZ * EMBD; i += 256) {
            int r = i >> 9, d = i & 511;
            inp[i] = emb[(size_t)s_tok[r] * EMBD + d];
        }
    }
}

// ---------------------------------------------------------------------------
extern "C" void kernel_launch(void* const* d_in, const int* in_sizes, int n_in,
                              void* d_out, int out_size, void* d_ws, size_t ws_size,
                              hipStream_t stream) {
    const float* x      = (const float*)d_in[0];
    const int*   labels = (const int*)  d_in[1];
    const void*  coin   =               d_in[2];
    const float* emb    = (const float*)d_in[3];
    const float* Wi     = (const float*)d_in[4];
    const float* Wh     = (const float*)d_in[5];
    const float* b      = (const float*)d_in[6];
    const float* Wo     = (const float*)d_in[7];
    const float* bo     = (const float*)d_in[8];

    float* ws   = (float*)d_ws;
    float* inp  = ws;                 // 16384
    float* hA   = ws + 16384;         // 16384
    float* hB   = ws + 32768;         // 16384
    float* c    = ws + 49152;         // 16384
    float* part = ws + 65536;         // 250*32*8 = 64000
    float* loss = ws + 129536;        // 1
    int*   flag = (int*)(ws + 129537);

    init_kernel<<<1, 256, 0, stream>>>(x, emb, coin, hA, c, inp, loss, flag);

    float* hsrc = hA;
    float* hdst = hB;
    for (int t = 0; t < 33; ++t) {
        cell_kernel<<<32, 256, 0, stream>>>(inp, Wi, Wh, b, hsrc, c, hdst);
        int tt = (t < 32) ? t : 0;  // final step never uses the label logit
        logits_kernel<<<NBLK_LOG, 256, 0, stream>>>(hdst, Wo, bo, labels, part, tt);
        reduce_kernel<<<1, 256, 0, stream>>>(part, labels, coin, flag, emb, inp,
                                             loss, (float*)d_out, t, t == 32 ? 1 : 0);
        float* tmp = hsrc; hsrc = hdst; hdst = tmp;
    }
}

// Round 2
// 3259.364 us; speedup vs baseline: 1.9066x; 1.9066x over previous
//
#include <hip/hip_runtime.h>
#include <math.h>

#define VOCABSZ 32000
#define EMBD 512
#define HIDD 512
#define BSZ 32
#define TLEN 32
#define G4 2048             // 4*HID
#define KSPLIT 8            // cell GEMM K-splits (128 k each)
#define NBLK_LOG 500        // logits blocks
#define LCOLS 64            // vocab cols per logits block
#define NP (NBLK_LOG * 32)  // partial entries per array

__device__ __forceinline__ float sigmoidf_(float x) { return 1.f / (1.f + expf(-x)); }

// ---------------------------------------------------------------------------
// init: h <- x, c <- 0, inp <- emb[START], loss <- 0, detect coin dtype
// ---------------------------------------------------------------------------
__global__ void init_kernel(const float* __restrict__ x,
                            const float* __restrict__ emb,
                            const void* __restrict__ coin,
                            float* __restrict__ h, float* __restrict__ c,
                            float* __restrict__ inp,
                            float* __restrict__ loss, int* __restrict__ flag) {
    int tid = threadIdx.x;
    if (tid == 0) {
        const unsigned int* cw = (const unsigned int*)coin;
        int f = 0;
        for (int i = 0; i < 256; ++i) if (cw[i] > 1u) f = 1;
        *flag = f;
        *loss = 0.f;
    }
    for (int i = tid; i < BSZ * HIDD; i += blockDim.x) {
        h[i] = x[i];
        c[i] = 0.f;
        inp[i] = emb[1 * EMBD + (i & (EMBD - 1))];  // START = 1
    }
}

// ---------------------------------------------------------------------------
// cell_mm: partial gates. grid 512 = colblk(64 x 32cols) * ksplit(8 x 128k).
// blockIdx.x = colblk*8 + ks. Thread: cidx=tid&31 (col), rowg=tid>>5 (4 rows).
// pg[ks][32][2048] partial sums in ws.
// ---------------------------------------------------------------------------
__global__ __launch_bounds__(256) void cell_mm_kernel(
    const float* __restrict__ inp, const float* __restrict__ Wi,
    const float* __restrict__ Wh, const float* __restrict__ hsrc,
    float* __restrict__ pg) {
    __shared__ float s_x[32][64];
    int tid = threadIdx.x;
    int ks = blockIdx.x & 7;
    int colblk = blockIdx.x >> 3;
    int cidx = tid & 31;
    int rowg = tid >> 5;                 // 0..7 -> 4 rows each
    int j = colblk * 32 + cidx;          // 0..2047

    const float* X = (ks < 4) ? inp : hsrc;
    const float* W = (ks < 4) ? Wi : Wh;
    int kb = (ks & 3) * 128;             // base k within the 512-row matrix

    float acc[4] = {0.f, 0.f, 0.f, 0.f};

    for (int ch = 0; ch < 2; ++ch) {     // two 64-k chunks
        int k0 = kb + ch * 64;
        for (int i = tid; i < 32 * 64; i += 256) {
            int r = i >> 6, kk = i & 63;
            s_x[r][kk] = X[r * HIDD + k0 + kk];
        }
        __syncthreads();
        #pragma unroll 4
        for (int kk = 0; kk < 64; ++kk) {
            float w = W[(size_t)(k0 + kk) * G4 + j];
            #pragma unroll
            for (int rr = 0; rr < 4; ++rr)
                acc[rr] += s_x[rowg * 4 + rr][kk] * w;
        }
        __syncthreads();
    }
    #pragma unroll
    for (int rr = 0; rr < 4; ++rr)
        pg[((size_t)ks * 32 + rowg * 4 + rr) * G4 + j] = acc[rr];
}

// ---------------------------------------------------------------------------
// cell_act: sum partials, add bias, gate activations, update c, write hdst.
// grid 64 x 256 : one thread per (row, j) with j in [0,512).
// ---------------------------------------------------------------------------
__global__ __launch_bounds__(256) void cell_act_kernel(
    const float* __restrict__ pg, const float* __restrict__ bias,
    float* __restrict__ c, float* __restrict__ hdst) {
    int idx = blockIdx.x * 256 + threadIdx.x;   // 0..16383
    int r = idx >> 9;
    int j = idx & 511;
    float i_ = bias[j], f_ = bias[j + 512], g_ = bias[j + 1024], o_ = bias[j + 1536];
    #pragma unroll
    for (int s = 0; s < KSPLIT; ++s) {
        const float* p = pg + (size_t)s * 32 * G4 + (size_t)r * G4;
        i_ += p[j];
        f_ += p[j + 512];
        g_ += p[j + 1024];
        o_ += p[j + 1536];
    }
    float ci = c[r * HIDD + j];
    float cn = sigmoidf_(f_) * ci + sigmoidf_(i_) * tanhf(g_);
    float hn = sigmoidf_(o_) * tanhf(cn);
    c[r * HIDD + j] = cn;
    hdst[r * HIDD + j] = hn;
}

// ---------------------------------------------------------------------------
// logits: grid 500 x 256thr; 64 vocab cols/block, float4 Wo loads.
// Thread: col4=tid&15 (16 float4 groups), rowg=tid>>4 (16 groups x 2 rows).
// Fused per-block softmax partials (SoA): pm, ps, pidx, plab, pstop.
// ---------------------------------------------------------------------------
__global__ __launch_bounds__(256) void logits_kernel(
    const float* __restrict__ h, const float* __restrict__ Wo,
    const float* __restrict__ bo, const int* __restrict__ labels,
    float* __restrict__ part, int t) {
    __shared__ float s_h[32][68];   // 16B-aligned stride, 2-way max on reads
    __shared__ float s_out[32][LCOLS];
    int tid = threadIdx.x;
    int col4 = tid & 15;
    int rowg = tid >> 4;            // 0..15 -> rows rowg*2, rowg*2+1
    int c0 = blockIdx.x * LCOLS + col4 * 4;

    float acc[2][4];
    #pragma unroll
    for (int r = 0; r < 2; ++r)
        #pragma unroll
        for (int q = 0; q < 4; ++q) acc[r][q] = 0.f;

    for (int kt = 0; kt < 8; ++kt) {   // 64 k per tile
        int k0 = kt * 64;
        for (int i = tid; i < 32 * 64; i += 256) {
            int r = i >> 6, kk = i & 63;
            s_h[r][kk] = h[r * HIDD + k0 + kk];
        }
        __syncthreads();
        #pragma unroll
        for (int kc = 0; kc < 8; ++kc) {   // 8-k sub-chunks
            float4 h0a = *(const float4*)&s_h[rowg * 2 + 0][kc * 8];
            float4 h0b = *(const float4*)&s_h[rowg * 2 + 0][kc * 8 + 4];
            float4 h1a = *(const float4*)&s_h[rowg * 2 + 1][kc * 8];
            float4 h1b = *(const float4*)&s_h[rowg * 2 + 1][kc * 8 + 4];
            float h0[8] = {h0a.x, h0a.y, h0a.z, h0a.w, h0b.x, h0b.y, h0b.z, h0b.w};
            float h1[8] = {h1a.x, h1a.y, h1a.z, h1a.w, h1b.x, h1b.y, h1b.z, h1b.w};
            #pragma unroll
            for (int kk = 0; kk < 8; ++kk) {
                int k = k0 + kc * 8 + kk;
                float4 w = *(const float4*)&Wo[(size_t)k * VOCABSZ + c0];
                acc[0][0] += h0[kk] * w.x; acc[0][1] += h0[kk] * w.y;
                acc[0][2] += h0[kk] * w.z; acc[0][3] += h0[kk] * w.w;
                acc[1][0] += h1[kk] * w.x; acc[1][1] += h1[kk] * w.y;
                acc[1][2] += h1[kk] * w.z; acc[1][3] += h1[kk] * w.w;
            }
        }
        __syncthreads();
    }
    float4 bq = *(const float4*)&bo[c0];
    #pragma unroll
    for (int r = 0; r < 2; ++r) {
        float4 v;
        v.x = acc[r][0] + bq.x; v.y = acc[r][1] + bq.y;
        v.z = acc[r][2] + bq.z; v.w = acc[r][3] + bq.w;
        *(float4*)&s_out[rowg * 2 + r][col4 * 4] = v;
    }
    __syncthreads();

    // per-row partial reduction over 64 cols: 8 slots per row
    int row = tid >> 3;
    int slot = tid & 7;
    float m = -INFINITY; int mi = 0;
    for (int cc = slot; cc < LCOLS; cc += 8) {
        float v = s_out[row][cc];
        int gidx = blockIdx.x * LCOLS + cc;
        if (v > m || (v == m && gidx < mi)) { m = v; mi = gidx; }
    }
    #pragma unroll
    for (int d = 1; d < 8; d <<= 1) {
        float om = __shfl_xor(m, d);
        int omi = __shfl_xor(mi, d);
        if (om > m || (om == m && omi < mi)) { m = om; mi = omi; }
    }
    float s = 0.f;
    for (int cc = slot; cc < LCOLS; cc += 8) s += expf(s_out[row][cc] - m);
    #pragma unroll
    for (int d = 1; d < 8; d <<= 1) s += __shfl_xor(s, d);

    if (slot == 0) {
        int e = blockIdx.x * 32 + row;
        part[e] = m;                       // pm
        part[NP + e] = s;                  // ps
        part[2 * NP + e] = __int_as_float(mi);  // pidx
        int lab = labels[row * TLEN + t];
        int lc = lab - blockIdx.x * LCOLS;
        part[3 * NP + e] = (lc >= 0 && lc < LCOLS) ? s_out[row][lc] : -INFINITY;
        int sc = 2 - blockIdx.x * LCOLS;   // STOP = 2
        part[4 * NP + e] = (sc >= 0 && sc < LCOLS) ? s_out[row][sc] : -INFINITY;
    }
}

// ---------------------------------------------------------------------------
// reduce: combine 500 block-partials per row; CE accumulate; token select;
// emb gather. 1 block x 1024 thr: 32 slots per row.
// ---------------------------------------------------------------------------
__global__ __launch_bounds__(1024) void reduce_kernel(
    const float* __restrict__ part, const int* __restrict__ labels,
    const void* __restrict__ coin, const int* __restrict__ flag,
    const float* __restrict__ emb, float* __restrict__ inp,
    float* __restrict__ loss, float* __restrict__ out,
    int t, int is_final) {
    __shared__ float s_ce[32];
    __shared__ int s_tok[32];
    int tid = threadIdx.x;
    int row = tid >> 5, slot = tid & 31;

    float M = -INFINITY, S = 0.f;
    float av = -INFINITY; int ai = 0;
    float lv = -INFINITY, sv = -INFINITY;
    for (int ib = slot; ib < NBLK_LOG; ib += 32) {
        int e = ib * 32 + row;
        float pm = part[e], ps = part[NP + e];
        int pi = __float_as_int(part[2 * NP + e]);
        float nM = fmaxf(M, pm);
        S = S * expf(M - nM) + ps * expf(pm - nM);
        M = nM;
        if (pm > av || (pm == av && pi < ai)) { av = pm; ai = pi; }
        lv = fmaxf(lv, part[3 * NP + e]);
        sv = fmaxf(sv, part[4 * NP + e]);
    }
    #pragma unroll
    for (int d = 1; d < 32; d <<= 1) {
        float oM = __shfl_xor(M, d), oS = __shfl_xor(S, d);
        float nM = fmaxf(M, oM);
        S = S * expf(M - nM) + oS * expf(oM - nM);
        M = nM;
        float oav = __shfl_xor(av, d); int oai = __shfl_xor(ai, d);
        if (oav > av || (oav == av && oai < ai)) { av = oav; ai = oai; }
        lv = fmaxf(lv, __shfl_xor(lv, d));
        sv = fmaxf(sv, __shfl_xor(sv, d));
    }
    if (slot == 0) {
        float logZ = M + logf(S);
        float ce = logZ - (is_final ? sv : lv);
        s_ce[row] = ce;
        if (!is_final) {
            int lab = labels[row * TLEN + t];
            int cn;
            if (*flag) cn = ((const unsigned char*)coin)[row * TLEN + t];
            else       cn = ((const int*)coin)[row * TLEN + t];
            s_tok[row] = cn ? ai : lab;
        }
    }
    __syncthreads();
    if (tid == 0) {
        float tot = 0.f;
        for (int r = 0; r < 32; ++r) tot += s_ce[r];
        float nl = *loss + tot;
        *loss = nl;
        if (is_final) *out = nl / 32.f;
    }
    if (!is_final) {
        __syncthreads();
        for (int i4 = tid; i4 < BSZ * EMBD / 4; i4 += 1024) {
            int r = i4 >> 7;               // (i4*4) >> 9
            int d = (i4 & 127) * 4;
            *(float4*)&inp[r * EMBD + d] =
                *(const float4*)&emb[(size_t)s_tok[r] * EMBD + d];
        }
    }
}

// ---------------------------------------------------------------------------
extern "C" void kernel_launch(void* const* d_in, const int* in_sizes, int n_in,
                              void* d_out, int out_size, void* d_ws, size_t ws_size,
                              hipStream_t stream) {
    const float* x      = (const float*)d_in[0];
    const int*   labels = (const int*)  d_in[1];
    const void*  coin   =               d_in[2];
    const float* emb    = (const float*)d_in[3];
    const float* Wi     = (const float*)d_in[4];
    const float* Wh     = (const float*)d_in[5];
    const float* b      = (const float*)d_in[6];
    const float* Wo     = (const float*)d_in[7];
    const float* bo     = (const float*)d_in[8];

    float* ws   = (float*)d_ws;
    float* inp  = ws;                      // 16384
    float* hA   = ws + 16384;              // 16384
    float* hB   = ws + 32768;              // 16384
    float* c    = ws + 49152;              // 16384
    float* pg   = ws + 65536;              // 8*32*2048 = 524288
    float* part = ws + 65536 + 524288;     // 5*NP = 80000
    float* loss = part + 5 * NP;           // 1
    int*   flag = (int*)(loss + 1);

    init_kernel<<<1, 256, 0, stream>>>(x, emb, coin, hA, c, inp, loss, flag);

    float* hsrc = hA;
    float* hdst = hB;
    for (int t = 0; t < 33; ++t) {
        cell_mm_kernel<<<512, 256, 0, stream>>>(inp, Wi, Wh, hsrc, pg);
        cell_act_kernel<<<64, 256, 0, stream>>>(pg, b, c, hdst);
        int tt = (t < 32) ? t : 0;  // final step never uses the label logit
        logits_kernel<<<NBLK_LOG, 256, 0, stream>>>(hdst, Wo, bo, labels, part, tt);
        reduce_kernel<<<1, 1024, 0, stream>>>(part, labels, coin, flag, emb, inp,
                                              loss, (float*)d_out, t, t == 32 ? 1 : 0);
        float* tmp = hsrc; hsrc = hdst; hdst = tmp;
    }
}

// Round 4
// 1736.148 us; speedup vs baseline: 3.5794x; 1.8774x over previous
//
#include <hip/hip_runtime.h>
#include <math.h>

#define VOCABSZ 32000
#define EMBD 512
#define HIDD 512
#define BSZ 32
#define TLEN 32
#define G4 2048             // 4*HID
#define KSPLIT 8            // cell GEMM K-splits (128 k each)
#define KS_LOG 2            // logits K-splits (256 k each)
#define LCB 128             // vocab cols per logits block
#define NCB (VOCABSZ / LCB) // 250

__device__ __forceinline__ float sigmoidf_(float x) { return 1.f / (1.f + expf(-x)); }

// ---------------------------------------------------------------------------
// init: h <- x, c <- 0, inp <- emb[START], ce_acc <- 0, detect coin dtype
// ---------------------------------------------------------------------------
__global__ void init_kernel(const float* __restrict__ x,
                            const float* __restrict__ emb,
                            const void* __restrict__ coin,
                            float* __restrict__ h, float* __restrict__ c,
                            float* __restrict__ inp,
                            float* __restrict__ ce_acc, int* __restrict__ flag) {
    int tid = threadIdx.x;
    if (tid == 0) {
        const unsigned int* cw = (const unsigned int*)coin;
        int f = 0;
        for (int i = 0; i < 256; ++i) if (cw[i] > 1u) f = 1;
        *flag = f;
    }
    if (tid < 32) ce_acc[tid] = 0.f;
    for (int i = tid; i < BSZ * HIDD; i += blockDim.x) {
        h[i] = x[i];
        c[i] = 0.f;
        inp[i] = emb[1 * EMBD + (i & (EMBD - 1))];  // START = 1
    }
}

// ---------------------------------------------------------------------------
// cell_mm: partial gates. grid 512 = colblk(64 x 32cols) * ksplit(8 x 128k).
// Stage X tile transposed [k][r] once, no mid-barriers, full unroll.
// Thread: cidx=tid&31 (1 col), rowg=tid>>5 (4 rows). pg[ks][32][2048].
// ---------------------------------------------------------------------------
__global__ __launch_bounds__(256) void cell_mm_kernel(
    const float* __restrict__ inp, const float* __restrict__ Wi,
    const float* __restrict__ Wh, const float* __restrict__ hsrc,
    float* __restrict__ pg) {
    __shared__ float s_x[128][36];       // [k][r], pad to 36 for b128 align
    int tid = threadIdx.x;
    int ks = blockIdx.x & 7;
    int colblk = blockIdx.x >> 3;
    int cidx = tid & 31;
    int rowg = tid >> 5;                 // 0..7 -> 4 rows each
    int j = colblk * 32 + cidx;          // 0..2047

    const float* X = (ks < 4) ? inp : hsrc;
    const float* W = (ks < 4) ? Wi : Wh;
    int kb = (ks & 3) * 128;

    #pragma unroll
    for (int p = 0; p < 16; ++p) {
        int idx = p * 256 + tid;
        int kk = idx & 127, r = idx >> 7;
        s_x[kk][r] = X[r * HIDD + kb + kk];
    }
    __syncthreads();

    float acc[4] = {0.f, 0.f, 0.f, 0.f};
    #pragma unroll 8
    for (int kk = 0; kk < 128; ++kk) {
        float w = W[(size_t)(kb + kk) * G4 + j];
        float4 xx = *(const float4*)&s_x[kk][rowg * 4];
        acc[0] += xx.x * w;
        acc[1] += xx.y * w;
        acc[2] += xx.z * w;
        acc[3] += xx.w * w;
    }
    #pragma unroll
    for (int rr = 0; rr < 4; ++rr)
        pg[((size_t)ks * 32 + rowg * 4 + rr) * G4 + j] = acc[rr];
}

// ---------------------------------------------------------------------------
// cell_act: sum partials, add bias, gate activations, update c, write hdst.
// ---------------------------------------------------------------------------
__global__ __launch_bounds__(256) void cell_act_kernel(
    const float* __restrict__ pg, const float* __restrict__ bias,
    float* __restrict__ c, float* __restrict__ hdst) {
    int idx = blockIdx.x * 256 + threadIdx.x;   // 0..16383
    int r = idx >> 9;
    int j = idx & 511;
    float i_ = bias[j], f_ = bias[j + 512], g_ = bias[j + 1024], o_ = bias[j + 1536];
    #pragma unroll
    for (int s = 0; s < KSPLIT; ++s) {
        const float* p = pg + (size_t)s * 32 * G4 + (size_t)r * G4;
        i_ += p[j];
        f_ += p[j + 512];
        g_ += p[j + 1024];
        o_ += p[j + 1536];
    }
    float ci = c[r * HIDD + j];
    float cn = sigmoidf_(f_) * ci + sigmoidf_(i_) * tanhf(g_);
    float hn = sigmoidf_(o_) * tanhf(cn);
    c[r * HIDD + j] = cn;
    hdst[r * HIDD + j] = hn;
}

// ---------------------------------------------------------------------------
// logits_mm: lp[ks][32][32000] partial GEMM. grid = NCB*KS_LOG = 500 blocks,
// 256 thr. Block: 128 cols x 32 rows x K=256. Thread: c4=tid&31 (4 cols),
// rg=tid>>5 (4 rows) -> 16 acc. Double-buffered LDS tiles of K=32, T14
// async-split staging (issue loads -> compute -> ds_write).
// ---------------------------------------------------------------------------
__global__ __launch_bounds__(256) void logits_mm_kernel(
    const float* __restrict__ h, const float* __restrict__ Wo,
    float* __restrict__ lp) {
    __shared__ float s_w[2][32][128];    // [buf][k][c] 16 KB each
    __shared__ float s_h[2][32][36];     // [buf][k][r] padded for b128 align
    int tid = threadIdx.x;
    int cb = blockIdx.x >> 1;            // 0..249
    int ks = blockIdx.x & 1;
    int c0 = cb * LCB;
    int kbase0 = ks * 256;
    int c4 = tid & 31;
    int rg = tid >> 5;
    int skk = tid & 31;                  // staging k within tile
    int sr = tid >> 5;                   // staging row group

    float acc[4][4];
    #pragma unroll
    for (int a = 0; a < 4; ++a)
        #pragma unroll
        for (int q = 0; q < 4; ++q) acc[a][q] = 0.f;

    // prologue: stage tile 0 into buf 0
    {
        int kb = kbase0;
        #pragma unroll
        for (int p = 0; p < 4; ++p) {
            int kk = p * 8 + sr;
            *(float4*)&s_w[0][kk][c4 * 4] =
                *(const float4*)&Wo[(size_t)(kb + kk) * VOCABSZ + c0 + c4 * 4];
            s_h[0][skk][p * 8 + sr] = h[(p * 8 + sr) * HIDD + kb + skk];
        }
    }
    __syncthreads();

    float4 wr[4];
    float hr[4];
    for (int tt = 0; tt < 8; ++tt) {
        int cur = tt & 1;
        if (tt < 7) {
            int kb = kbase0 + (tt + 1) * 32;
            #pragma unroll
            for (int p = 0; p < 4; ++p) {
                int kk = p * 8 + sr;
                wr[p] = *(const float4*)&Wo[(size_t)(kb + kk) * VOCABSZ + c0 + c4 * 4];
                hr[p] = h[(p * 8 + sr) * HIDD + kb + skk];
            }
        }
        #pragma unroll
        for (int kk = 0; kk < 32; ++kk) {
            float4 w = *(const float4*)&s_w[cur][kk][c4 * 4];
            float4 hh = *(const float4*)&s_h[cur][kk][rg * 4];
            acc[0][0] += hh.x * w.x; acc[0][1] += hh.x * w.y;
            acc[0][2] += hh.x * w.z; acc[0][3] += hh.x * w.w;
            acc[1][0] += hh.y * w.x; acc[1][1] += hh.y * w.y;
            acc[1][2] += hh.y * w.z; acc[1][3] += hh.y * w.w;
            acc[2][0] += hh.z * w.x; acc[2][1] += hh.z * w.y;
            acc[2][2] += hh.z * w.z; acc[2][3] += hh.z * w.w;
            acc[3][0] += hh.w * w.x; acc[3][1] += hh.w * w.y;
            acc[3][2] += hh.w * w.z; acc[3][3] += hh.w * w.w;
        }
        __syncthreads();
        if (tt < 7) {
            int nb = cur ^ 1;
            #pragma unroll
            for (int p = 0; p < 4; ++p) {
                int kk = p * 8 + sr;
                *(float4*)&s_w[nb][kk][c4 * 4] = wr[p];
                s_h[nb][skk][p * 8 + sr] = hr[p];
            }
        }
        __syncthreads();
    }

    #pragma unroll
    for (int rr = 0; rr < 4; ++rr) {
        float4 v;
        v.x = acc[rr][0]; v.y = acc[rr][1]; v.z = acc[rr][2]; v.w = acc[rr][3];
        *(float4*)&lp[((size_t)ks * 32 + rg * 4 + rr) * VOCABSZ + c0 + c4 * 4] = v;
    }
}

// ---------------------------------------------------------------------------
// softmax: one block per row (32 x 1024). logit = lp0 + lp1 + bo. Computes
// logZ, argmax (lowest-index ties), label/STOP logit, CE accumulate, token
// select, emb gather -> inp.
// VOCAB = 32000 = 8000 float4 chunks; 1024 threads x 8 iters = 8192 chunks,
// so chunks with ch >= 8000 are masked to -INF (inert in max/sum/label:
// every thread keeps >= 28 valid elements so the running max stays finite).
// ---------------------------------------------------------------------------
__global__ __launch_bounds__(1024) void softmax_kernel(
    const float* __restrict__ lp, const float* __restrict__ bo,
    const int* __restrict__ labels, const void* __restrict__ coin,
    const int* __restrict__ flag, const float* __restrict__ emb,
    float* __restrict__ inp, float* __restrict__ ce_acc,
    int t, int is_final) {
    __shared__ float w_m[16], w_s[16], w_av[16], w_lab[16], w_stop[16];
    __shared__ int w_ai[16];
    __shared__ int s_tok;
    int row = blockIdx.x;
    int tid = threadIdx.x;
    int lab = labels[row * TLEN + (is_final ? 0 : t)];
    const float* lp0 = lp + (size_t)row * VOCABSZ;
    const float* lp1 = lp + (size_t)(32 + row) * VOCABSZ;

    float v[32];
    #pragma unroll
    for (int j = 0; j < 8; ++j) {
        int ch = j * 1024 + tid;
        if (ch < VOCABSZ / 4) {
            float4 a = *(const float4*)&lp0[ch * 4];
            float4 b4 = *(const float4*)&lp1[ch * 4];
            float4 bb = *(const float4*)&bo[ch * 4];
            v[j * 4 + 0] = a.x + b4.x + bb.x;
            v[j * 4 + 1] = a.y + b4.y + bb.y;
            v[j * 4 + 2] = a.z + b4.z + bb.z;
            v[j * 4 + 3] = a.w + b4.w + bb.w;
        } else {
            v[j * 4 + 0] = -INFINITY;
            v[j * 4 + 1] = -INFINITY;
            v[j * 4 + 2] = -INFINITY;
            v[j * 4 + 3] = -INFINITY;
        }
    }
    float m = -INFINITY; int mi = 0;
    float slab = -INFINITY, sstop = -INFINITY;
    #pragma unroll
    for (int i = 0; i < 32; ++i) {
        int idx = ((i >> 2) * 1024 + tid) * 4 + (i & 3);
        if (v[i] > m) { m = v[i]; mi = idx; }
        if (idx == lab) slab = v[i];
        if (idx == 2) sstop = v[i];
    }
    float s = 0.f;
    #pragma unroll
    for (int i = 0; i < 32; ++i) s += expf(v[i] - m);

    // wave reduce (64 lanes)
    #pragma unroll
    for (int d = 1; d < 64; d <<= 1) {
        float om = __shfl_xor(m, d);
        int omi = __shfl_xor(mi, d);
        float os = __shfl_xor(s, d);
        float nM = fmaxf(m, om);
        s = s * expf(m - nM) + os * expf(om - nM);
        if (om > m || (om == m && omi < mi)) { mi = omi; }
        m = nM;
        slab = fmaxf(slab, __shfl_xor(slab, d));
        sstop = fmaxf(sstop, __shfl_xor(sstop, d));
    }
    int wv = tid >> 6;
    if ((tid & 63) == 0) {
        w_m[wv] = m; w_s[wv] = s; w_av[wv] = m; w_ai[wv] = mi;
        w_lab[wv] = slab; w_stop[wv] = sstop;
    }
    __syncthreads();
    if (tid == 0) {
        float M = -INFINITY, S = 0.f, AV = -INFINITY, LB = -INFINITY, ST = -INFINITY;
        int AI = 0;
        for (int k = 0; k < 16; ++k) {
            float pm = w_m[k], ps = w_s[k];
            float nM = fmaxf(M, pm);
            S = S * expf(M - nM) + ps * expf(pm - nM);
            M = nM;
            if (w_av[k] > AV || (w_av[k] == AV && w_ai[k] < AI)) { AV = w_av[k]; AI = w_ai[k]; }
            LB = fmaxf(LB, w_lab[k]);
            ST = fmaxf(ST, w_stop[k]);
        }
        float logZ = M + logf(S);
        float ce = logZ - (is_final ? ST : LB);
        ce_acc[row] += ce;
        if (!is_final) {
            int cn;
            if (*flag) cn = ((const unsigned char*)coin)[row * TLEN + t];
            else       cn = ((const int*)coin)[row * TLEN + t];
            s_tok = cn ? AI : lab;
        }
    }
    __syncthreads();
    if (!is_final && tid < 128) {
        *(float4*)&inp[row * EMBD + tid * 4] =
            *(const float4*)&emb[(size_t)s_tok * EMBD + tid * 4];
    }
}

// ---------------------------------------------------------------------------
__global__ void finalize_kernel(const float* __restrict__ ce_acc,
                                float* __restrict__ out) {
    if (threadIdx.x == 0) {
        float tot = 0.f;
        for (int r = 0; r < 32; ++r) tot += ce_acc[r];
        *out = tot / 32.f;
    }
}

// ---------------------------------------------------------------------------
extern "C" void kernel_launch(void* const* d_in, const int* in_sizes, int n_in,
                              void* d_out, int out_size, void* d_ws, size_t ws_size,
                              hipStream_t stream) {
    const float* x      = (const float*)d_in[0];
    const int*   labels = (const int*)  d_in[1];
    const void*  coin   =               d_in[2];
    const float* emb    = (const float*)d_in[3];
    const float* Wi     = (const float*)d_in[4];
    const float* Wh     = (const float*)d_in[5];
    const float* b      = (const float*)d_in[6];
    const float* Wo     = (const float*)d_in[7];
    const float* bo     = (const float*)d_in[8];

    float* ws     = (float*)d_ws;
    float* inp    = ws;                      // 16384
    float* hA     = ws + 16384;              // 16384
    float* hB     = ws + 32768;              // 16384
    float* c      = ws + 49152;              // 16384
    float* pg     = ws + 65536;              // 8*32*2048 = 524288
    float* lp     = ws + 589824;             // 2*32*32000 = 2048000
    float* ce_acc = ws + 2637824;            // 32
    int*   flag   = (int*)(ws + 2637856);

    init_kernel<<<1, 256, 0, stream>>>(x, emb, coin, hA, c, inp, ce_acc, flag);

    float* hsrc = hA;
    float* hdst = hB;
    for (int t = 0; t < 33; ++t) {
        cell_mm_kernel<<<512, 256, 0, stream>>>(inp, Wi, Wh, hsrc, pg);
        cell_act_kernel<<<64, 256, 0, stream>>>(pg, b, c, hdst);
        logits_mm_kernel<<<NCB * KS_LOG, 256, 0, stream>>>(hdst, Wo, lp);
        softmax_kernel<<<32, 1024, 0, stream>>>(lp, bo, labels, coin, flag, emb,
                                                inp, ce_acc, t, t == 32 ? 1 : 0);
        float* tmp = hsrc; hsrc = hdst; hdst = tmp;
    }
    finalize_kernel<<<1, 64, 0, stream>>>(ce_acc, (float*)d_out);
}